// Round 1
// baseline (341.286 us; speedup 1.0000x reference)
//
#include <hip/hip_runtime.h>
#include <hip/hip_bf16.h>
#include <math.h>

#define NB 2
#define NHH 16
#define TT 1024
#define HDD 64
#define NSS 3
#define HH 1024
#define MMR 2048  // NB*TT

typedef float f4 __attribute__((ext_vector_type(4)));
typedef short bf16x8 __attribute__((ext_vector_type(8)));
typedef unsigned short u16;
typedef u16 u16x4 __attribute__((ext_vector_type(4)));

__device__ inline u16 f2bf(float f) {
    union { float f; unsigned u; } v; v.f = f;
    unsigned r = (v.u + 0x7FFFu + ((v.u >> 16) & 1u)) >> 16;
    return (u16)r;
}
__device__ inline float bf2f(u16 u) {
    union { unsigned u; float f; } v; v.u = ((unsigned)u) << 16;
    return v.f;
}

__device__ inline float red16max(float v) {
    v = fmaxf(v, __shfl_xor(v, 1));
    v = fmaxf(v, __shfl_xor(v, 2));
    v = fmaxf(v, __shfl_xor(v, 4));
    v = fmaxf(v, __shfl_xor(v, 8));
    return v;
}
__device__ inline float red16sum(float v) {
    v += __shfl_xor(v, 1);
    v += __shfl_xor(v, 2);
    v += __shfl_xor(v, 4);
    v += __shfl_xor(v, 8);
    return v;
}
__device__ inline float red64sum(float v) {
    v += __shfl_xor(v, 1);
    v += __shfl_xor(v, 2);
    v += __shfl_xor(v, 4);
    v += __shfl_xor(v, 8);
    v += __shfl_xor(v, 16);
    v += __shfl_xor(v, 32);
    return v;
}

// ---------------- fp32 -> bf16 convert (vectorized) ----------------
__global__ __launch_bounds__(256) void k_cvt(const float* __restrict__ src,
                                             u16* __restrict__ dst, int n4) {
    int i = blockIdx.x * 256 + threadIdx.x;
    if (i >= n4) return;
    f4 v = ((const f4*)src)[i];
    u16x4 o;
    o[0] = f2bf(v[0]); o[1] = f2bf(v[1]); o[2] = f2bf(v[2]); o[3] = f2bf(v[3]);
    ((u16x4*)dst)[i] = o;
}

// ---------------- V transpose: [BH, T, 64] f32 -> [BH, 64, T] bf16 ----------------
__global__ __launch_bounds__(256) void k_vtrans(const float* __restrict__ V,
                                                u16* __restrict__ Vt) {
    __shared__ float tile[64][65];
    int bh = blockIdx.y, t0 = blockIdx.x * 64;
    int r = threadIdx.x >> 2, c0 = (threadIdx.x & 3) * 16;
    const float* vp = V + ((size_t)bh * TT + t0) * HDD;
#pragma unroll
    for (int j = 0; j < 16; j += 4) {
        f4 v = *(const f4*)(vp + r * HDD + c0 + j);
        tile[r][c0 + j + 0] = v[0]; tile[r][c0 + j + 1] = v[1];
        tile[r][c0 + j + 2] = v[2]; tile[r][c0 + j + 3] = v[3];
    }
    __syncthreads();
    int d = threadIdx.x >> 2, x0 = (threadIdx.x & 3) * 16;
    u16* op = Vt + ((size_t)bh * HDD + d) * TT + t0 + x0;
#pragma unroll
    for (int j = 0; j < 16; j += 4) {
        u16x4 o;
        o[0] = f2bf(tile[x0 + j + 0][d]); o[1] = f2bf(tile[x0 + j + 1][d]);
        o[2] = f2bf(tile[x0 + j + 2][d]); o[3] = f2bf(tile[x0 + j + 3][d]);
        *(u16x4*)(op + j) = o;
    }
}

// ---------------- GEMM: C[M,N] = A[M,K] * B[N,K]^T + bias ----------------
// EPI 0: out row-major [M,N] fp32.  EPI 1: scatter to ctx [B,NH,T,HD].
template <int EPI>
__global__ __launch_bounds__(256) void k_gemm_bt(const u16* __restrict__ A,
                                                 const u16* __restrict__ Bm,
                                                 const float* __restrict__ bias,
                                                 float* __restrict__ out) {
    const int K = 1024, N = 1024;
    int w = threadIdx.x >> 6, l = threadIdx.x & 63, lr = l & 15, lg = l >> 4;
    int m0 = blockIdx.y * 64 + w * 16;
    int n0 = blockIdx.x * 64;
    const u16* ap = A + (size_t)(m0 + lr) * K + lg * 8;
    const u16* bp = Bm + (size_t)(n0 + lr) * K + lg * 8;
    f4 z4 = {0.f, 0.f, 0.f, 0.f};
    f4 acc[4] = {z4, z4, z4, z4};
#pragma unroll 2
    for (int kk = 0; kk < K; kk += 32) {
        bf16x8 a  = *(const bf16x8*)(ap + kk);
        bf16x8 b0 = *(const bf16x8*)(bp + kk);
        bf16x8 b1 = *(const bf16x8*)(bp + 16 * K + kk);
        bf16x8 b2 = *(const bf16x8*)(bp + 32 * K + kk);
        bf16x8 b3 = *(const bf16x8*)(bp + 48 * K + kk);
        acc[0] = __builtin_amdgcn_mfma_f32_16x16x32_bf16(a, b0, acc[0], 0, 0, 0);
        acc[1] = __builtin_amdgcn_mfma_f32_16x16x32_bf16(a, b1, acc[1], 0, 0, 0);
        acc[2] = __builtin_amdgcn_mfma_f32_16x16x32_bf16(a, b2, acc[2], 0, 0, 0);
        acc[3] = __builtin_amdgcn_mfma_f32_16x16x32_bf16(a, b3, acc[3], 0, 0, 0);
    }
#pragma unroll
    for (int cf = 0; cf < 4; ++cf) {
        int col = n0 + cf * 16 + lr;
        float bs = bias[col];
#pragma unroll
        for (int r = 0; r < 4; ++r) {
            int row = m0 + lg * 4 + r;
            float v = acc[cf][r] + bs;
            if (EPI == 0) {
                out[(size_t)row * N + col] = v;
            } else {
                int b = row >> 10, t = row & 1023, nh = col >> 6, hd = col & 63;
                out[(((size_t)(b * NHH + nh)) * TT + t) * HDD + hd] = v;
            }
        }
    }
}

// ---------------- LayerNorm + ReLU -> bf16 ----------------
__global__ __launch_bounds__(256) void k_lnrelu(const float* __restrict__ X,
                                                const float* __restrict__ g,
                                                const float* __restrict__ bta,
                                                u16* __restrict__ xr) {
    int row = blockIdx.x;
    f4 v = ((const f4*)(X + (size_t)row * HH))[threadIdx.x];
    float s = v[0] + v[1] + v[2] + v[3];
    float s2 = v[0] * v[0] + v[1] * v[1] + v[2] * v[2] + v[3] * v[3];
    s = red64sum(s);
    s2 = red64sum(s2);
    __shared__ float red[8];
    int w = threadIdx.x >> 6, l = threadIdx.x & 63;
    if (l == 0) { red[w] = s; red[w + 4] = s2; }
    __syncthreads();
    float S1 = red[0] + red[1] + red[2] + red[3];
    float S2 = red[4] + red[5] + red[6] + red[7];
    float mu = S1 * (1.0f / 1024.0f);
    float var = S2 * (1.0f / 1024.0f) - mu * mu;
    float rstd = rsqrtf(var + 1e-5f);
    f4 gv = ((const f4*)g)[threadIdx.x];
    f4 bv = ((const f4*)bta)[threadIdx.x];
    u16x4 o;
#pragma unroll
    for (int j = 0; j < 4; ++j) {
        float y = (v[j] - mu) * rstd * gv[j] + bv[j];
        y = fmaxf(y, 0.f);
        o[j] = f2bf(y);
    }
    ((u16x4*)(xr + (size_t)row * HH))[threadIdx.x] = o;
}

// ---------------- q formation (closed-form PCN refinement) ----------------
__global__ __launch_bounds__(256) void k_qform(const float* __restrict__ que,
                                               const float* __restrict__ hyp,
                                               const float* __restrict__ rn,
                                               const float* __restrict__ ctx,
                                               float* __restrict__ q) {
    int i = blockIdx.x * 256 + threadIdx.x;  // vec4 index over [B,NH,T,HD]
    const float A5 = 0.9509900499f;
    const float CC = 1.0f - A5;
    const float CH = 0.1f * A5;
    const float C0 = 0.0096059601f, C1 = 0.0097029900f, C2 = 0.0098010000f, C3 = 0.0099f;
    const int NQ4 = (NB * NHH * TT * HDD) / 4;  // 524288
    f4 qv = ((const f4*)que)[i];
    f4 cv = ((const f4*)ctx)[i];
    f4 base = A5 * qv + CC * cv;
#pragma unroll
    for (int s = 0; s < 3; ++s) {
        f4 h  = ((const f4*)hyp)[s * NQ4 + i];
        f4 r0 = ((const f4*)rn)[(s * 4 + 0) * NQ4 + i];
        f4 r1 = ((const f4*)rn)[(s * 4 + 1) * NQ4 + i];
        f4 r2 = ((const f4*)rn)[(s * 4 + 2) * NQ4 + i];
        f4 r3 = ((const f4*)rn)[(s * 4 + 3) * NQ4 + i];
        f4 o = base + CH * h + C0 * r0 + C1 * r1 + C2 * r2 + C3 * r3;
        ((f4*)q)[s * NQ4 + i] = o;
    }
}

// ---------------- flash attention + energy stats ----------------
// grid: bi = ((s*B+b)*NH + h)*16 + qt ; block 256 (4 waves, 16 q-rows each)
__global__ __launch_bounds__(256) void k_attn(const float* __restrict__ q,
                                              const u16* __restrict__ Kb,
                                              const u16* __restrict__ Vt,
                                              float* __restrict__ part) {
    int bi = blockIdx.x;
    int qt = bi & 15, h = (bi >> 4) & 15, sb = bi >> 8;
    int b = sb & 1;
    int bh = b * NHH + h;
    int w = threadIdx.x >> 6, l = threadIdx.x & 63, lr = l & 15, lg = l >> 4;
    int t0 = qt * 64;
    f4 z4 = {0.f, 0.f, 0.f, 0.f};

    // Q fragments (scale 1/8 folded into bf16 conversion)
    const float* qp = q + (((size_t)(sb * NHH + h)) * TT + t0 + w * 16 + lr) * HDD + lg * 8;
    bf16x8 aq0, aq1;
    {
        f4 v0 = *(const f4*)(qp);
        f4 v1 = *(const f4*)(qp + 4);
        f4 v2 = *(const f4*)(qp + 32);
        f4 v3 = *(const f4*)(qp + 36);
#pragma unroll
        for (int j = 0; j < 4; ++j) {
            aq0[j]     = (short)f2bf(v0[j] * 0.125f);
            aq0[4 + j] = (short)f2bf(v1[j] * 0.125f);
            aq1[j]     = (short)f2bf(v2[j] * 0.125f);
            aq1[4 + j] = (short)f2bf(v3[j] * 0.125f);
        }
    }
    const u16* kp = Kb + ((size_t)bh * TT) * HDD;
    const u16* vp = Vt + ((size_t)bh * HDD) * TT;

    f4 acco[4] = {z4, z4, z4, z4};
    float mrow[4], zrow[4], wrow[4];
#pragma unroll
    for (int r = 0; r < 4; ++r) { mrow[r] = -3.0e38f; zrow[r] = 0.f; wrow[r] = 0.f; }

    __shared__ u16 plds[4][1024];  // per-wave 16x64 P tile, XOR-swizzled

    for (int kt = 0; kt < 16; ++kt) {
        const u16* kpt = kp + kt * 64 * HDD;
        f4 sc[4];
#pragma unroll
        for (int cf = 0; cf < 4; ++cf) {
            bf16x8 bk0 = *(const bf16x8*)(kpt + (cf * 16 + lr) * HDD + lg * 8);
            bf16x8 bk1 = *(const bf16x8*)(kpt + (cf * 16 + lr) * HDD + 32 + lg * 8);
            f4 t = __builtin_amdgcn_mfma_f32_16x16x32_bf16(aq0, bk0, z4, 0, 0, 0);
            sc[cf] = __builtin_amdgcn_mfma_f32_16x16x32_bf16(aq1, bk1, t, 0, 0, 0);
        }
        float p[4][4];
#pragma unroll
        for (int r = 0; r < 4; ++r) {
            float mx = fmaxf(fmaxf(sc[0][r], sc[1][r]), fmaxf(sc[2][r], sc[3][r]));
            mx = red16max(mx);
            float mn = fmaxf(mrow[r], mx);
            float fac = __expf(mrow[r] - mn);
            mrow[r] = mn;
            zrow[r] *= fac; wrow[r] *= fac;
            acco[0][r] *= fac; acco[1][r] *= fac; acco[2][r] *= fac; acco[3][r] *= fac;
#pragma unroll
            for (int cf = 0; cf < 4; ++cf) {
                float pe = __expf(sc[cf][r] - mn);
                p[cf][r] = pe;
                zrow[r] += pe;
                wrow[r] += pe * sc[cf][r];
            }
        }
        // P -> LDS (bf16), XOR swizzle on ushort-index bits 3..5
#pragma unroll
        for (int r = 0; r < 4; ++r) {
            int row = lg * 4 + r;
            int swz = (row & 7) << 3;
#pragma unroll
            for (int cf = 0; cf < 4; ++cf) {
                plds[w][(row * 64 + cf * 16 + lr) ^ swz] = f2bf(p[cf][r]);
            }
        }
        bf16x8 pa0 = *(const bf16x8*)&plds[w][(lr * 64 + lg * 8) ^ ((lr & 7) << 3)];
        bf16x8 pa1 = *(const bf16x8*)&plds[w][(lr * 64 + 32 + lg * 8) ^ ((lr & 7) << 3)];
        const u16* vpt = vp + kt * 64;
#pragma unroll
        for (int cf = 0; cf < 4; ++cf) {
            bf16x8 bv0 = *(const bf16x8*)(vpt + (cf * 16 + lr) * TT + lg * 8);
            bf16x8 bv1 = *(const bf16x8*)(vpt + (cf * 16 + lr) * TT + 32 + lg * 8);
            acco[cf] = __builtin_amdgcn_mfma_f32_16x16x32_bf16(pa0, bv0, acco[cf], 0, 0, 0);
            acco[cf] = __builtin_amdgcn_mfma_f32_16x16x32_bf16(pa1, bv1, acco[cf], 0, 0, 0);
        }
    }

    // per-row finalize: out_mag & entropy
    float magw = 0.f, entw = 0.f;
#pragma unroll
    for (int r = 0; r < 4; ++r) {
        float zz = red16sum(zrow[r]);
        float ww = red16sum(wrow[r]);
        float ssq = acco[0][r] * acco[0][r] + acco[1][r] * acco[1][r] +
                    acco[2][r] * acco[2][r] + acco[3][r] * acco[3][r];
        ssq = red16sum(ssq);
        float inv = 1.0f / zz;
        magw += sqrtf(ssq) * inv;
        entw += mrow[r] + __logf(zz) - ww * inv;
    }
    magw += __shfl_xor(magw, 16); magw += __shfl_xor(magw, 32);
    entw += __shfl_xor(entw, 16); entw += __shfl_xor(entw, 32);

    // align: sum_d q[t,d]*k[t,d] over this block's 64 rows
    int arow = threadIdx.x & 63, ad0 = (threadIdx.x >> 6) * 16;
    const float* qa = q + (((size_t)(sb * NHH + h)) * TT + t0 + arow) * HDD + ad0;
    const u16* ka = Kb + (((size_t)bh) * TT + t0 + arow) * HDD + ad0;
    float al = 0.f;
#pragma unroll
    for (int j = 0; j < 16; j += 4) {
        f4 qv4 = *(const f4*)(qa + j);
        al += qv4[0] * bf2f(ka[j]) + qv4[1] * bf2f(ka[j + 1]) +
              qv4[2] * bf2f(ka[j + 2]) + qv4[3] * bf2f(ka[j + 3]);
    }
    al = red64sum(al);

    __shared__ float red[4][3];
    if (l == 0) { red[w][0] = magw; red[w][1] = entw; red[w][2] = al; }
    __syncthreads();
    if (threadIdx.x == 0) {
        part[bi * 3 + 0] = red[0][0] + red[1][0] + red[2][0] + red[3][0];
        part[bi * 3 + 1] = red[0][1] + red[1][1] + red[2][1] + red[3][1];
        part[bi * 3 + 2] = red[0][2] + red[1][2] + red[2][2] + red[3][2];
    }
}

// ---------------- energy reduce + softmax over samples ----------------
__global__ void k_finalize(const float* __restrict__ part, float* __restrict__ probs) {
    int w = threadIdx.x >> 6, l = threadIdx.x & 63;
    __shared__ float eng[6];
    if (w < 6) {
        float a0 = 0.f, a1 = 0.f, a2 = 0.f;
        for (int i = l; i < 256; i += 64) {
            const float* pp = part + (size_t)(w * 256 + i) * 3;
            a0 += pp[0]; a1 += pp[1]; a2 += pp[2];
        }
        a0 = red64sum(a0); a1 = red64sum(a1); a2 = red64sum(a2);
        if (l == 0) {
            const float inv = 1.0f / 16384.0f;
            eng[w] = a0 * inv - 0.1f * (a1 * inv) - 0.05f * (a2 * inv);
        }
    }
    __syncthreads();
    if (threadIdx.x < 2) {
        int b = threadIdx.x;
        float e0 = -eng[0 + b], e1 = -eng[2 + b], e2 = -eng[4 + b];
        float mx = fmaxf(e0, fmaxf(e1, e2));
        float x0 = __expf(e0 - mx), x1 = __expf(e1 - mx), x2 = __expf(e2 - mx);
        float inv = 1.0f / (x0 + x1 + x2);
        probs[0 + b] = x0 * inv;
        probs[2 + b] = x1 * inv;
        probs[4 + b] = x2 * inv;
    }
}

// ---------------- selected = sum_s probs[s,b] * q[s] ----------------
__global__ __launch_bounds__(256) void k_select(const float* __restrict__ q,
                                                const float* __restrict__ probs,
                                                float* __restrict__ out) {
    int i = blockIdx.x * 256 + threadIdx.x;  // vec4 over [B,NH,T,HD]
    int b = i >> 18;                          // 262144 vec4 per batch
    const int NQ4 = 524288;
    float p0 = probs[0 + b], p1 = probs[2 + b], p2 = probs[4 + b];
    f4 v = p0 * ((const f4*)q)[i] + p1 * ((const f4*)q)[NQ4 + i] + p2 * ((const f4*)q)[2 * NQ4 + i];
    ((f4*)out)[i] = v;
}

extern "C" void kernel_launch(void* const* d_in, const int* in_sizes, int n_in,
                              void* d_out, int out_size, void* d_ws, size_t ws_size,
                              hipStream_t stream) {
    const float* queries = (const float*)d_in[0];
    const float* keys    = (const float*)d_in[1];
    const float* values  = (const float*)d_in[2];
    const float* hs      = (const float*)d_in[3];
    const float* W1      = (const float*)d_in[4];
    const float* b1      = (const float*)d_in[5];
    const float* ln_g    = (const float*)d_in[6];
    const float* ln_b    = (const float*)d_in[7];
    const float* W2      = (const float*)d_in[8];
    const float* b2      = (const float*)d_in[9];
    const float* hyp     = (const float*)d_in[10];
    const float* rn      = (const float*)d_in[11];
    float* out = (float*)d_out;
    char* ws = (char*)d_ws;

    const size_t MB = 1024ull * 1024ull;
    // qq occupies [0, 24MB); MLP temporaries live inside it (dead before k_qform writes qq)
    float* qq   = (float*)(ws);                 // 24 MB  [S,B,NH,T,HD] fp32
    u16*   hs_b = (u16*)(ws + 0 * MB);          //  4 MB  (dead after gemm1)
    u16*   w1_b = (u16*)(ws + 4 * MB);          //  2 MB
    u16*   w2_b = (u16*)(ws + 6 * MB);          //  2 MB
    float* X    = (float*)(ws + 8 * MB);        //  8 MB  (dead after lnrelu)
    u16*   xr   = (u16*)(ws + 16 * MB);         //  4 MB  (dead after gemm2)
    float* ctx  = (float*)(ws + 24 * MB);       //  8 MB
    u16*   k_b  = (u16*)(ws + 32 * MB);         //  4 MB
    u16*   vt_b = (u16*)(ws + 36 * MB);         //  4 MB
    float* part = (float*)(ws + 40 * MB);       // 18 KB
    float* probs= (float*)(ws + 40 * MB + 65536);

    k_cvt<<<2048, 256, 0, stream>>>(hs, hs_b, 524288);
    k_cvt<<<1024, 256, 0, stream>>>(W1, w1_b, 262144);
    k_cvt<<<1024, 256, 0, stream>>>(W2, w2_b, 262144);
    k_cvt<<<2048, 256, 0, stream>>>(keys, k_b, 524288);
    k_vtrans<<<dim3(16, 32), 256, 0, stream>>>(values, vt_b);

    k_gemm_bt<0><<<dim3(16, 32), 256, 0, stream>>>(hs_b, w1_b, b1, X);
    k_lnrelu<<<2048, 256, 0, stream>>>(X, ln_g, ln_b, xr);
    k_gemm_bt<1><<<dim3(16, 32), 256, 0, stream>>>(xr, w2_b, b2, ctx);

    k_qform<<<2048, 256, 0, stream>>>(queries, hyp, rn, ctx, qq);
    k_attn<<<1536, 256, 0, stream>>>(qq, k_b, vt_b, part);
    k_finalize<<<1, 384, 0, stream>>>(part, probs);
    k_select<<<2048, 256, 0, stream>>>(qq, probs, out);

    hipMemcpyAsync(out + 2097152, keys, 2097152 * sizeof(float),
                   hipMemcpyDeviceToDevice, stream);
    hipMemcpyAsync(out + 4194304, values, 2097152 * sizeof(float),
                   hipMemcpyDeviceToDevice, stream);
}